// Round 1
// baseline (268.205 us; speedup 1.0000x reference)
//
#include <hip/hip_runtime.h>
#include <hip/hip_bf16.h>

typedef unsigned int u32;
typedef unsigned long long u64;

#define BB 16
#define LL 8192
#define CC 512
#define KK 64
#define CAP 256           // candidate buffer capacity per column
#define LCH 64            // l-chunks per batch (parallelism for pass 1)
#define LPB (LL / LCH)    // 128 rows per block
#define THRESH 2.1f       // count above: mean~146, sigma~12 -> 64<=n<=256 w/ ~7 sigma margin

// ---- order-preserving fp32 <-> u32 key transforms ----
__device__ __forceinline__ u32 flip_bits(u32 u) {
  return u ^ ((u & 0x80000000u) ? 0xFFFFFFFFu : 0x80000000u);
}
__device__ __forceinline__ u32 unflip_bits(u32 f) {
  return (f & 0x80000000u) ? (f ^ 0x80000000u) : ~f;
}
__device__ __forceinline__ u64 u64max(u64 a, u64 b) { return a > b ? a : b; }
__device__ __forceinline__ u64 u64min(u64 a, u64 b) { return a < b ? a : b; }

// ---------------- Pass 1: streaming threshold filter ----------------
// grid = BB*LCH blocks, 128 threads; each thread owns 4 consecutive channels
// (float4 load = 16B/lane, fully coalesced). Survivors appended to per-column
// candidate lists with per-column atomic counters.
__global__ __launch_bounds__(128) void kcollect(const float* __restrict__ x,
                                                u32* __restrict__ cnt,
                                                u64* __restrict__ cand) {
  int blk = blockIdx.x;
  int b = blk >> 6;          // / LCH
  int chunk = blk & (LCH - 1);
  int t = threadIdx.x;       // 0..127
  int base_ch = b * CC + t * 4;
  const float4* p =
      reinterpret_cast<const float4*>(x + ((size_t)b * LL + (size_t)chunk * LPB) * CC) + t;
#pragma unroll 8
  for (int i = 0; i < LPB; ++i) {
    float4 v = p[(size_t)i * (CC / 4)];
    u32 l = (u32)(chunk * LPB + i);
    float vs[4] = {v.x, v.y, v.z, v.w};
#pragma unroll
    for (int q = 0; q < 4; ++q) {
      if (vs[q] > THRESH) {
        u32 pos = atomicAdd(&cnt[base_ch + q], 1u);
        if (pos < CAP) {
          cand[(size_t)(base_ch + q) * CAP + pos] =
              (((u64)flip_bits(__float_as_uint(vs[q]))) << 32) | l;
        }
      }
    }
  }
}

// ---------------- Pass 2: per-column top-64 select + index sort ----------------
// One wave per column. Fast path: bitonic sort of 256 candidate keys (4/lane,
// register-only via shfl_xor), take top 64, re-sort by index, write.
// Slow path (n<64 or n>CAP or no ws): exact iterative max-extraction over the
// raw column. All branches are wave-uniform; no LDS, no __syncthreads.
__global__ __launch_bounds__(256) void kselect(const float* __restrict__ x,
                                               const u32* __restrict__ cnt,
                                               const u64* __restrict__ cand,
                                               float* __restrict__ out,
                                               int force_slow) {
  int lane = threadIdx.x & 63;
  int ch = blockIdx.x * (blockDim.x >> 6) + (threadIdx.x >> 6);
  if (ch >= BB * CC) return;
  int b = ch >> 9;           // / CC
  int c = ch & (CC - 1);
  u32 n = force_slow ? 0u : cnt[ch];
  u64 sel;
  if (n >= (u32)KK && n <= (u32)CAP) {
    // element e = r*64 + lane, r = 0..3
    u64 kk[4];
#pragma unroll
    for (int r = 0; r < 4; ++r) {
      int idx = r * 64 + lane;
      kk[r] = (idx < (int)n) ? cand[(size_t)ch * CAP + idx] : 0ull;
    }
    // bitonic sort 256 keys DESCENDING, fully in registers
#pragma unroll
    for (int k = 2; k <= 256; k <<= 1) {
#pragma unroll
      for (int j = k >> 1; j > 0; j >>= 1) {
        if (j >= 64) {
          int rj = j >> 6;
#pragma unroll
          for (int r = 0; r < 4; ++r) {
            int pr = r ^ rj;
            if (pr > r) {
              int e = r * 64 + lane;
              bool descb = ((e & k) == 0);
              u64 a = kk[r], bq = kk[pr];
              u64 mx = u64max(a, bq), mn = u64min(a, bq);
              kk[r] = descb ? mx : mn;
              kk[pr] = descb ? mn : mx;
            }
          }
        } else {
#pragma unroll
          for (int r = 0; r < 4; ++r) {
            u64 other = __shfl_xor(kk[r], j, 64);
            int e = r * 64 + lane;
            bool upper = (lane & j) != 0;
            bool descb = ((e & k) == 0);
            bool keepmax = descb ? !upper : upper;
            kk[r] = keepmax ? u64max(kk[r], other) : u64min(kk[r], other);
          }
        }
      }
    }
    sel = kk[0];  // lane i holds i-th largest key
  } else {
    // exact slow path: 64 rounds of wave-reduce max over keys < prev
    u64 prev = ~0ull;
    sel = 0;
    const float* col = x + (size_t)b * LL * CC + c;
    for (int r = 0; r < KK; ++r) {
      u64 local = 0;
      for (int t = 0; t < LL / 64; ++t) {
        int l = t * 64 + lane;
        float v = col[(size_t)l * CC];
        u64 key = (((u64)flip_bits(__float_as_uint(v))) << 32) | (u32)l;
        if (key < prev) local = u64max(local, key);
      }
#pragma unroll
      for (int m = 32; m > 0; m >>= 1) local = u64max(local, __shfl_xor(local, m, 64));
      if (lane == r) sel = local;
      prev = local;
    }
  }
  // Re-key by (index, value) and sort ASCENDING across the wave -> original order
  u32 f = (u32)(sel >> 32);
  u32 l = (u32)sel;
  u64 s2 = (((u64)l) << 32) | f;
#pragma unroll
  for (int k = 2; k <= 64; k <<= 1) {
#pragma unroll
    for (int j = k >> 1; j > 0; j >>= 1) {
      u64 other = __shfl_xor(s2, j, 64);
      bool upper = (lane & j) != 0;
      bool ascb = ((lane & k) == 0);
      bool keepmax = ascb ? upper : !upper;
      s2 = keepmax ? u64max(s2, other) : u64min(s2, other);
    }
  }
  float val = __uint_as_float(unflip_bits((u32)s2));
  out[((size_t)b * KK + lane) * CC + c] = val;
}

extern "C" void kernel_launch(void* const* d_in, const int* in_sizes, int n_in,
                              void* d_out, int out_size, void* d_ws, size_t ws_size,
                              hipStream_t stream) {
  const float* x = (const float*)d_in[0];
  float* out = (float*)d_out;
  const size_t cnt_bytes = (size_t)BB * CC * sizeof(u32);
  const size_t need = cnt_bytes + (size_t)BB * CC * CAP * sizeof(u64);
  if (d_ws != nullptr && ws_size >= need) {
    u32* cnt = (u32*)d_ws;
    u64* cand = (u64*)((char*)d_ws + cnt_bytes);
    hipMemsetAsync(cnt, 0, cnt_bytes, stream);
    kcollect<<<BB * LCH, 128, 0, stream>>>(x, cnt, cand);
    kselect<<<(BB * CC) / 4, 256, 0, stream>>>(x, cnt, cand, out, 0);
  } else {
    // no/insufficient workspace: exact (slow) path for every column
    kselect<<<(BB * CC) / 4, 256, 0, stream>>>(x, nullptr, nullptr, out, 1);
  }
}

// Round 2
// 104.076 us; speedup vs baseline: 2.5770x; 2.5770x over previous
//
#include <hip/hip_runtime.h>

typedef unsigned int u32;
typedef unsigned long long u64;

#define BB 16
#define LL 8192
#define CC 512
#define KK 64
#define LCH 256          // L-chunks per batch
#define LPB 32           // rows per chunk (bitmask width)
#define THRESH 2.1f      // survivors/column: mean~146 sigma~12 -> 64<=n<=256 w/ ~7sigma margin

// ---- order-preserving fp32 <-> u32 key transforms ----
__device__ __forceinline__ u32 flip_bits(u32 u) {
  return u ^ ((u & 0x80000000u) ? 0xFFFFFFFFu : 0x80000000u);
}
__device__ __forceinline__ u32 unflip_bits(u32 f) {
  return (f & 0x80000000u) ? (f ^ 0x80000000u) : ~f;
}
__device__ __forceinline__ u64 u64max(u64 a, u64 b) { return a > b ? a : b; }
__device__ __forceinline__ u64 u64min(u64 a, u64 b) { return a < b ? a : b; }

// ---------------- Pass 1: streaming survivor bitmask (no atomics) ----------------
// grid = BB*LCH = 4096 blocks x 128 threads (8192 waves = 32/CU).
// Thread t owns columns 4t..4t+3 (float4 loads, fully coalesced).
// Emits one u32 bitmask per (column, 32-row chunk): bit i = (x[row]>THRESH).
// Store is one uint4 per thread -> 1KB/wave coalesced. Fixed size, exact.
__global__ __launch_bounds__(128) void kbitmask(const float* __restrict__ x,
                                                u32* __restrict__ bm) {
  int blk = blockIdx.x;
  int b = blk >> 8;
  int chunk = blk & (LCH - 1);
  int t = threadIdx.x;
  const float4* p =
      reinterpret_cast<const float4*>(x + ((size_t)b * LL + (size_t)chunk * LPB) * CC) + t;
  u32 m0 = 0, m1 = 0, m2 = 0, m3 = 0;
#pragma unroll
  for (int i = 0; i < LPB; ++i) {
    float4 v = p[(size_t)i * (CC / 4)];
    m0 |= ((u32)(v.x > THRESH)) << i;
    m1 |= ((u32)(v.y > THRESH)) << i;
    m2 |= ((u32)(v.z > THRESH)) << i;
    m3 |= ((u32)(v.w > THRESH)) << i;
  }
  uint4* dst = reinterpret_cast<uint4*>(bm + (size_t)(b * LCH + chunk) * CC) + t;
  *dst = make_uint4(m0, m1, m2, m3);
}

// ---------------- Pass 2: per-column top-64 from bitmasks ----------------
// One wave per column (4 waves/block). Lane owns 4 chunks: popc + shfl scan ->
// offsets; extract bits, gather values from x, stage <=256 keys in LDS; register
// bitonic sort 256 desc -> top 64 -> index re-sort -> write. Exact slow path
// backstop if total<64 or total>256. All barriers unconditional.
__global__ __launch_bounds__(256) void kselect(const float* __restrict__ x,
                                               const u32* __restrict__ bm,
                                               float* __restrict__ out,
                                               int force_slow) {
  __shared__ u64 lds[4 * 256];
  int lane = threadIdx.x & 63;
  int w = threadIdx.x >> 6;
  int ch = blockIdx.x * 4 + w;
  int b = ch >> 9;
  int c = ch & (CC - 1);
  u64* wl = lds + w * 256;
  const float* colp = x + (size_t)b * LL * CC + c;

  // zero-pad all 256 slots of this wave's region
#pragma unroll
  for (int r = 0; r < 4; ++r) wl[r * 64 + lane] = 0;
  __syncthreads();

  u32 total = 0;
  if (!force_slow) {
    u32 mk[4];
    u32 cnt = 0;
#pragma unroll
    for (int j = 0; j < 4; ++j) {
      mk[j] = bm[((size_t)(b * LCH) + (u32)(lane * 4 + j)) * CC + c];
      cnt += __popc(mk[j]);
    }
    // inclusive scan across 64 lanes
    u32 inc = cnt;
#pragma unroll
    for (int d = 1; d < 64; d <<= 1) {
      u32 o = __shfl_up(inc, d, 64);
      if (lane >= d) inc += o;
    }
    u32 pos = inc - cnt;  // exclusive offset
    total = __shfl(inc, 63, 64);
#pragma unroll
    for (int j = 0; j < 4; ++j) {
      u32 m = mk[j];
      int base = (lane * 4 + j) * LPB;
      while (m) {
        int bit = __builtin_ctz(m);
        m &= m - 1;
        int l = base + bit;
        float v = colp[(size_t)l * CC];
        u64 key = (((u64)flip_bits(__float_as_uint(v))) << 32) | (u32)l;
        if (pos < 256) wl[pos] = key;
        pos++;
      }
    }
  }
  __syncthreads();

  u64 sel;
  if (!force_slow && total >= (u32)KK && total <= 256u) {
    // element e = r*64 + lane
    u64 kk[4];
#pragma unroll
    for (int r = 0; r < 4; ++r) kk[r] = wl[r * 64 + lane];
    // bitonic sort 256 keys DESCENDING, registers + shfl only
#pragma unroll
    for (int k = 2; k <= 256; k <<= 1) {
#pragma unroll
      for (int j = k >> 1; j > 0; j >>= 1) {
        if (j >= 64) {
          int rj = j >> 6;
#pragma unroll
          for (int r = 0; r < 4; ++r) {
            int pr = r ^ rj;
            if (pr > r) {
              int e = r * 64 + lane;
              bool descb = ((e & k) == 0);
              u64 a = kk[r], bq = kk[pr];
              u64 mx = u64max(a, bq), mn = u64min(a, bq);
              kk[r] = descb ? mx : mn;
              kk[pr] = descb ? mn : mx;
            }
          }
        } else {
#pragma unroll
          for (int r = 0; r < 4; ++r) {
            u64 other = __shfl_xor(kk[r], j, 64);
            int e = r * 64 + lane;
            bool upper = (lane & j) != 0;
            bool descb = ((e & k) == 0);
            bool keepmax = descb ? !upper : upper;
            kk[r] = keepmax ? u64max(kk[r], other) : u64min(kk[r], other);
          }
        }
      }
    }
    sel = kk[0];  // lane i holds i-th largest key
  } else {
    // exact slow path: 64 rounds of wave-reduce max over keys < prev
    u64 prev = ~0ull;
    sel = 0;
    for (int r = 0; r < KK; ++r) {
      u64 local = 0;
      for (int t = 0; t < LL / 64; ++t) {
        int l = t * 64 + lane;
        float v = colp[(size_t)l * CC];
        u64 key = (((u64)flip_bits(__float_as_uint(v))) << 32) | (u32)l;
        if (key < prev) local = u64max(local, key);
      }
#pragma unroll
      for (int m = 32; m > 0; m >>= 1) local = u64max(local, __shfl_xor(local, m, 64));
      if (lane == r) sel = local;
      prev = local;
    }
  }

  // Re-key by (index, value) and sort ASCENDING across the wave -> original order
  u32 f = (u32)(sel >> 32);
  u32 l = (u32)sel;
  u64 s2 = (((u64)l) << 32) | f;
#pragma unroll
  for (int k = 2; k <= 64; k <<= 1) {
#pragma unroll
    for (int j = k >> 1; j > 0; j >>= 1) {
      u64 other = __shfl_xor(s2, j, 64);
      bool upper = (lane & j) != 0;
      bool ascb = ((lane & k) == 0);
      bool keepmax = ascb ? upper : !upper;
      s2 = keepmax ? u64max(s2, other) : u64min(s2, other);
    }
  }
  float val = __uint_as_float(unflip_bits((u32)s2));
  out[((size_t)b * KK + lane) * CC + c] = val;
}

extern "C" void kernel_launch(void* const* d_in, const int* in_sizes, int n_in,
                              void* d_out, int out_size, void* d_ws, size_t ws_size,
                              hipStream_t stream) {
  const float* x = (const float*)d_in[0];
  float* out = (float*)d_out;
  const size_t need = (size_t)BB * LCH * CC * sizeof(u32);  // 8 MB of bitmasks
  if (d_ws != nullptr && ws_size >= need) {
    u32* bm = (u32*)d_ws;
    kbitmask<<<BB * LCH, 128, 0, stream>>>(x, bm);
    kselect<<<(BB * CC) / 4, 256, 0, stream>>>(x, bm, out, 0);
  } else {
    // no/insufficient workspace: exact (slow) path for every column
    kselect<<<(BB * CC) / 4, 256, 0, stream>>>(x, nullptr, out, 1);
  }
}